// Round 16
// baseline (1142.889 us; speedup 1.0000x reference)
//
#include <hip/hip_runtime.h>

#define T 4096
#define EP 16                     // steps per barrier epoch (R13-verified optimum)
#define RING 32                   // LDS ring depth (disjoint writer/reader halves mod 32)
#define NEP (T / EP + 2)          // 258 epochs: pipeline depth 2 epochs

// tanh(x) = 1 - 2/(exp(2x)+1). Branch-free, ~1e-6 err.
__device__ __forceinline__ float fast_tanh(float x) {
    float e = __expf(2.0f * x);
    float r = __builtin_amdgcn_rcpf(e + 1.0f);
    return fmaf(-2.0f, r, 1.0f);
}

// 16/64-scalar residency anchors (once per epoch; near-zero cost).
#define ANCHOR16(a, b) asm volatile("" : \
    "+v"((a)[(b)+0]),  "+v"((a)[(b)+1]),  "+v"((a)[(b)+2]),  "+v"((a)[(b)+3]),  \
    "+v"((a)[(b)+4]),  "+v"((a)[(b)+5]),  "+v"((a)[(b)+6]),  "+v"((a)[(b)+7]),  \
    "+v"((a)[(b)+8]),  "+v"((a)[(b)+9]),  "+v"((a)[(b)+10]), "+v"((a)[(b)+11]), \
    "+v"((a)[(b)+12]), "+v"((a)[(b)+13]), "+v"((a)[(b)+14]), "+v"((a)[(b)+15]))
#define ANCHOR64(a) do { ANCHOR16(a, 0); ANCHOR16(a, 16); \
                         ANCHOR16(a, 32); ANCHOR16(a, 48); } while (0)

// ---------------------------------------------------------------------------
// R16: R15 kernel (893us seq, absmax 0.0) with hybrid h-copy transport.
// Stall analysis: v1 = h[i^16] is consumed at KBLOCK16, only ~60-70 issue-cyc
// after its ds_bpermute issues; LDS-path latency ~100-120 cyc -> ~40-50 cyc
// lgkmcnt stall per step. v2/v3 (consumed at +32/+48 ops) are covered.
// Fix: v1 via v_permlane16_swap_b32 (pure VALU, ~8 cyc; R8 proved this path
// bit-exact) with runtime polarity probe + bpermute fallback; v2/v3 stay on
// bpermute. Values bit-identical -> absmax must stay 0.0.
// ---------------------------------------------------------------------------
#define ROTF(acc, v, w, R) \
    asm("v_fmac_f32_dpp %0, %1, %2 row_ror:" #R " row_mask:0xf bank_mask:0xf" \
        : "+v"(acc) : "v"(v), "v"(w))

// Hazard-guarded copy: dst is safe as a DPP source for anything sequenced
// after this blob (s_nop 1 = 2 wait states).
#define MOVNOP(dst, src) \
    asm("v_mov_b32 %0, %1\n\ts_nop 1" : "=v"(dst) : "v"(src))

// Two-register permlane16 swap (gfx950). s_nop 1 guards the preceding v_mov
// producers (hazard recognizer can't see into asm).
#define PLSWAP16(a, b) \
    asm("s_nop 1\n\tv_permlane16_swap_b32 %0, %1" : "+v"(a), "+v"(b))

// One 16-rotation block: r=0 plain fma, r=1..15 fused DPP. acc index = r & 3.
#define KBLOCK(v, wd, B) do { \
    a0 = fmaf((v), (wd)[(B) + 0], a0); \
    ROTF(a1, (v), (wd)[(B) + 1],  1);  ROTF(a2, (v), (wd)[(B) + 2],  2); \
    ROTF(a3, (v), (wd)[(B) + 3],  3);  ROTF(a0, (v), (wd)[(B) + 4],  4); \
    ROTF(a1, (v), (wd)[(B) + 5],  5);  ROTF(a2, (v), (wd)[(B) + 6],  6); \
    ROTF(a3, (v), (wd)[(B) + 7],  7);  ROTF(a0, (v), (wd)[(B) + 8],  8); \
    ROTF(a1, (v), (wd)[(B) + 9],  9);  ROTF(a2, (v), (wd)[(B) +10], 10); \
    ROTF(a3, (v), (wd)[(B) +11], 11);  ROTF(a0, (v), (wd)[(B) +12], 12); \
    ROTF(a1, (v), (wd)[(B) +13], 13);  ROTF(a2, (v), (wd)[(B) +14], 14); \
    ROTF(a3, (v), (wd)[(B) +15], 15); \
} while (0)

// One recurrence step. bpermutes (v2/v3) issue first (LDS pipe, consumed at
// +32/+48 DPP ops -> latency covered); v1 built in-VALU via permlane16_swap
// (no LDS latency; first DPP read >=17 insts after its write). v1/v2/v3
// values bit-identical to the all-bpermute path.
__device__ __forceinline__ float rnn_step_dpp(const float (&wd)[64], float init, float hp,
                                              bool usePerm, bool e16,
                                              int a16, int a32, int a48) {
    const int hb = __float_as_int(hp);
    const int b2i = __builtin_amdgcn_ds_bpermute(a32, hb);   // h[i^32]
    const int b3i = __builtin_amdgcn_ds_bpermute(a48, hb);   // h[i^48]
    float v1;
    if (usePerm) {                     // wave-uniform branch
        float s16a = hp, s16b = hp;
        PLSWAP16(s16a, s16b);
        v1 = e16 ? s16b : s16a;        // h[i^16], pure VALU
    } else {
        v1 = __int_as_float(__builtin_amdgcn_ds_bpermute(a16, hb));
    }
    float hpD; MOVNOP(hpD, hp);        // hp IS a VALU write -> keep guard
    float a0 = init, a1 = 0.f, a2 = 0.f, a3 = 0.f;
    KBLOCK(hpD, wd, 0);
    KBLOCK(v1, wd, 16);
    const float v2 = __int_as_float(b2i); KBLOCK(v2, wd, 32);
    const float v3 = __int_as_float(b3i); KBLOCK(v3, wd, 48);
    return fast_tanh((a0 + a1) + (a2 + a3));
}

// Pre-permuted weight row for the DPP decomposition (verified R6/R7, absmax 0).
__device__ __forceinline__ void load_wdpp(const float* __restrict__ W, int lane,
                                          bool dirplus, float (&wd)[64]) {
#pragma unroll
    for (int m = 0; m < 64; ++m) {
        const int k = m >> 4, r = m & 15;
        const int lowoff = dirplus ? r : ((16 - r) & 15);
        const int j = ((lane & 48) | ((lane + lowoff) & 15)) ^ (k << 4);
        wd[m] = W[lane * 64 + j];
    }
}

// ---------------------------------------------------------------------------
// prep: pre[s][t][i] = b_ih0[i] + b_hh0[i] + sum_d W_ih0[i][d] * in[0,t,d]
// Only batch element 0 of x / y matters (reference uses e[0], o[0] only).
// ---------------------------------------------------------------------------
__global__ void prep_kernel(const float* __restrict__ x, const float* __restrict__ y,
                            const float* __restrict__ eW, const float* __restrict__ ebi,
                            const float* __restrict__ ebh,
                            const float* __restrict__ oW, const float* __restrict__ obi,
                            const float* __restrict__ obh,
                            float* __restrict__ pre)
{
    int idx = blockIdx.x * blockDim.x + threadIdx.x;   // 2*T*64 threads
    int i = idx & 63;
    int t = (idx >> 6) & (T - 1);
    int s = idx >> 18;
    const float* in = s ? y : x;          // batch 0 = first T*3 floats
    const float* W  = s ? oW : eW;        // [64][3]
    const float* bi = s ? obi : ebi;
    const float* bh = s ? obh : ebh;
    float v = bi[i] + bh[i]
            + W[i*3+0]*in[t*3+0] + W[i*3+1]*in[t*3+1] + W[i*3+2]*in[t*3+2];
    pre[idx] = v;
}

// ---------------------------------------------------------------------------
// seq: grid=2 (one block per RNN), 4 specialized waves, barrier per EP epoch.
//   wave0 @ epoch k: h0[t] = tanh(p[t] + Whh0@h0[t-1]), t in [16k, 16k+16)
//   wave1/wave2 @ epoch k: q[t] = b1 + Wih1@h0[t], t-split halves of [16k-16,16k)
//   wave3 @ epoch k: h1[t] = tanh(q[t] + Whh1@h1[t-1]), t in [16k-32, 16k-16)
// Ring safety at EP=16 (mod-32 ring): disjoint halves; readers >=1 barrier
// behind writers (verified R13).
// ---------------------------------------------------------------------------
__global__ __launch_bounds__(256, 1) void seq_kernel(
    const float* __restrict__ pre,            // [2][T][64]
    const float* __restrict__ eWhh0, const float* __restrict__ eWih1,
    const float* __restrict__ eWhh1, const float* __restrict__ ebih1,
    const float* __restrict__ ebhh1,
    const float* __restrict__ oWhh0, const float* __restrict__ oWih1,
    const float* __restrict__ oWhh1, const float* __restrict__ obih1,
    const float* __restrict__ obhh1,
    float* __restrict__ hlast)                // [2][64]
{
    const int s    = blockIdx.x;
    const int wv   = threadIdx.x >> 6;
    const int lane = threadIdx.x & 63;

    __shared__ __align__(16) float h0ring[RING][64];
    __shared__ __align__(16) float qring[RING][64];

    const float* p = pre + s * T * 64;

    // Probe the hardware row_ror direction (wave-uniform result; R6-verified).
    const int got = __builtin_amdgcn_update_dpp(0, lane, 0x121, 0xF, 0xF, false);
    const bool dirplus = ((got & 15) == ((lane + 1) & 15));
    // bpermute byte-addresses for the XOR-copies
    const int a16 = (lane ^ 16) << 2;
    const int a32 = (lane ^ 32) << 2;
    const int a48 = (lane ^ 48) << 2;

    // Probe permlane16_swap polarity (wave-uniform; R8-verified machinery).
    const bool evenrow = ((lane >> 4) & 1) == 0;
    int p16a = lane, p16b = lane;
    PLSWAP16(p16a, p16b);
    const bool p16A = __all((evenrow ? p16b : p16a) == (lane ^ 16));
    const bool p16B = __all((evenrow ? p16a : p16b) == (lane ^ 16));
    const bool usePerm = (p16A || p16B);
    const bool e16 = (evenrow == p16A);   // select-b iff (evenrow XNOR A-polarity)

    if (wv == 0) {
        // ---------- layer-0 recurrence wave ----------
        const float* Whh0 = s ? oWhh0 : eWhh0;
        float wd[64];
        load_wdpp(Whh0, lane, dirplus, wd);

        float hp = 0.f;                        // h0[t-1]
        float pc[EP], pn[EP];
#pragma unroll
        for (int i = 0; i < EP; ++i) pc[i] = p[i * 64 + lane];

        for (int k = 0; k < NEP; ++k) {
            ANCHOR64(wd);                      // keep weight row resident
            const int base = k * EP;
            // prefetch next epoch's p (consumed next epoch -> latency hidden)
#pragma unroll
            for (int i = 0; i < EP; ++i) {
                int t = base + EP + i;
                pn[i] = (t < T) ? p[t * 64 + lane] : 0.f;
            }
            if (base < T) {                    // wave-uniform scalar branch
#pragma unroll
                for (int i = 0; i < EP; ++i) {
                    hp = rnn_step_dpp(wd, pc[i], hp, usePerm, e16, a16, a32, a48);
                    h0ring[(base + i) & (RING - 1)][lane] = hp;   // publish
                }
            }
#pragma unroll
            for (int i = 0; i < EP; ++i) pc[i] = pn[i];
            __syncthreads();
        }
    } else if (wv <= 2) {
        // ---------- helper waves: layer-1 input projection, t-split ----------
        const float* Wih1 = s ? oWih1 : eWih1;
        const float  b1   = s ? (obih1[lane] + obhh1[lane])
                              : (ebih1[lane] + ebhh1[lane]);
        float wi[64];
#pragma unroll
        for (int j = 0; j < 64; ++j) wi[j] = Wih1[lane * 64 + j];

        const int i0 = (wv - 1) * (EP / 2);    // wave1: t 0..7, wave2: t 8..15

        for (int k = 0; k < NEP; ++k) {
            ANCHOR64(wi);
            const int base = k * EP - EP;
            if (base >= 0 && base < T) {
#pragma unroll
                for (int i = 0; i < EP / 2; ++i) {
                    const int t = base + i0 + i;
                    const float4* hv = (const float4*)h0ring[t & (RING - 1)];
                    float q[4] = { b1, 0.f, 0.f, 0.f };
#pragma unroll
                    for (int j4 = 0; j4 < 16; ++j4) {
                        float4 u = hv[j4];
                        q[0] = fmaf(wi[4*j4+0], u.x, q[0]);
                        q[1] = fmaf(wi[4*j4+1], u.y, q[1]);
                        q[2] = fmaf(wi[4*j4+2], u.z, q[2]);
                        q[3] = fmaf(wi[4*j4+3], u.w, q[3]);
                    }
                    qring[t & (RING - 1)][lane] = (q[0] + q[1]) + (q[2] + q[3]);
                }
            }
            __syncthreads();
        }
    } else {
        // ---------- layer-1 recurrence wave ----------
        const float* Whh1 = s ? oWhh1 : eWhh1;
        float wd[64];
        load_wdpp(Whh1, lane, dirplus, wd);

        float hp = 0.f;                        // h1[t-1]
        for (int k = 0; k < NEP; ++k) {
            ANCHOR64(wd);
            const int base = k * EP - 2 * EP;
            if (base >= 0) {                   // base+EP-1 <= T-1 by construction
                float qb[EP];
#pragma unroll
                for (int i = 0; i < EP; ++i)   // all written >=1 epoch ago
                    qb[i] = qring[(base + i) & (RING - 1)][lane];
#pragma unroll
                for (int i = 0; i < EP; ++i)
                    hp = rnn_step_dpp(wd, qb[i], hp, usePerm, e16, a16, a32, a48);
            }
            __syncthreads();
        }
        hlast[s * 64 + lane] = hp;             // h1[T-1]
    }
}

// ---------------------------------------------------------------------------
// head: e0 = fce_w@hx + fce_b ; o0 = fco_w@hy + fco_b ; zz=[e0,o0,z];
//       h = relu(fc1_w@zz + fc1_b) ; out = fc2_w@h + fc2_b
// ---------------------------------------------------------------------------
__global__ void head_kernel(const float* __restrict__ hlast,   // [2][64]
                            const float* __restrict__ z,
                            const float* __restrict__ fce_w, const float* __restrict__ fce_b,
                            const float* __restrict__ fco_w, const float* __restrict__ fco_b,
                            const float* __restrict__ fc1_w, const float* __restrict__ fc1_b,
                            const float* __restrict__ fc2_w, const float* __restrict__ fc2_b,
                            float* __restrict__ out)            // [5]
{
    const int lane = threadIdx.x;   // 64 threads
    __shared__ float zz[9];
    __shared__ float hh[64];

    if (lane < 2) {
        float sacc = fce_b[lane];
        for (int j = 0; j < 64; ++j) sacc += fce_w[lane * 64 + j] * hlast[j];
        zz[lane] = sacc;
    } else if (lane < 4) {
        int r = lane - 2;
        float sacc = fco_b[r];
        for (int j = 0; j < 64; ++j) sacc += fco_w[r * 64 + j] * hlast[64 + j];
        zz[lane] = sacc;
    } else if (lane < 9) {
        zz[lane] = z[lane - 4];
    }
    __syncthreads();

    float sacc = fc1_b[lane];
#pragma unroll
    for (int j = 0; j < 9; ++j) sacc += fc1_w[lane * 9 + j] * zz[j];
    hh[lane] = fmaxf(sacc, 0.f);
    __syncthreads();

    if (lane < 5) {
        float o = fc2_b[lane];
        for (int i = 0; i < 64; ++i) o += fc2_w[lane * 64 + i] * hh[i];
        out[lane] = o;
    }
}

// ---------------------------------------------------------------------------
extern "C" void kernel_launch(void* const* d_in, const int* in_sizes, int n_in,
                              void* d_out, int out_size, void* d_ws, size_t ws_size,
                              hipStream_t stream)
{
    const float* x      = (const float*)d_in[0];
    const float* y      = (const float*)d_in[1];
    const float* z      = (const float*)d_in[2];
    const float* e_Wih0 = (const float*)d_in[3];
    const float* e_Whh0 = (const float*)d_in[4];
    const float* e_bih0 = (const float*)d_in[5];
    const float* e_bhh0 = (const float*)d_in[6];
    const float* e_Wih1 = (const float*)d_in[7];
    const float* e_Whh1 = (const float*)d_in[8];
    const float* e_bih1 = (const float*)d_in[9];
    const float* e_bhh1 = (const float*)d_in[10];
    const float* o_Wih0 = (const float*)d_in[11];
    const float* o_Whh0 = (const float*)d_in[12];
    const float* o_bih0 = (const float*)d_in[13];
    const float* o_bhh0 = (const float*)d_in[14];
    const float* o_Wih1 = (const float*)d_in[15];
    const float* o_Whh1 = (const float*)d_in[16];
    const float* o_bih1 = (const float*)d_in[17];
    const float* o_bhh1 = (const float*)d_in[18];
    const float* fce_w  = (const float*)d_in[19];
    const float* fce_b  = (const float*)d_in[20];
    const float* fco_w  = (const float*)d_in[21];
    const float* fco_b  = (const float*)d_in[22];
    const float* fc1_w  = (const float*)d_in[23];
    const float* fc1_b  = (const float*)d_in[24];
    const float* fc2_w  = (const float*)d_in[25];
    const float* fc2_b  = (const float*)d_in[26];

    float* pre   = (float*)d_ws;            // 2*T*64 floats = 2 MB
    float* hlast = pre + 2 * T * 64;        // 128 floats
    float* out   = (float*)d_out;

    prep_kernel<<<(2 * T * 64) / 256, 256, 0, stream>>>(
        x, y, e_Wih0, e_bih0, e_bhh0, o_Wih0, o_bih0, o_bhh0, pre);

    seq_kernel<<<2, 256, 0, stream>>>(
        pre,
        e_Whh0, e_Wih1, e_Whh1, e_bih1, e_bhh1,
        o_Whh0, o_Wih1, o_Whh1, o_bih1, o_bhh1,
        hlast);

    head_kernel<<<1, 64, 0, stream>>>(
        hlast, z, fce_w, fce_b, fco_w, fco_b, fc1_w, fc1_b, fc2_w, fc2_b, out);
}

// Round 17
// 998.186 us; speedup vs baseline: 1.1450x; 1.1450x over previous
//
#include <hip/hip_runtime.h>

#define T 4096
#define EP 16                     // steps per barrier epoch (R13-verified optimum)
#define RING 32                   // LDS ring depth (disjoint writer/reader halves mod 32)
#define NEP (T / EP + 2)          // 258 epochs: pipeline depth 2 epochs

// tanh(x) = 1 - 2/(exp(2x)+1). Branch-free, ~1e-6 err.
__device__ __forceinline__ float fast_tanh(float x) {
    float e = __expf(2.0f * x);
    float r = __builtin_amdgcn_rcpf(e + 1.0f);
    return fmaf(-2.0f, r, 1.0f);
}

// 16/64-scalar residency anchors (once per epoch; near-zero cost).
#define ANCHOR16(a, b) asm volatile("" : \
    "+v"((a)[(b)+0]),  "+v"((a)[(b)+1]),  "+v"((a)[(b)+2]),  "+v"((a)[(b)+3]),  \
    "+v"((a)[(b)+4]),  "+v"((a)[(b)+5]),  "+v"((a)[(b)+6]),  "+v"((a)[(b)+7]),  \
    "+v"((a)[(b)+8]),  "+v"((a)[(b)+9]),  "+v"((a)[(b)+10]), "+v"((a)[(b)+11]), \
    "+v"((a)[(b)+12]), "+v"((a)[(b)+13]), "+v"((a)[(b)+14]), "+v"((a)[(b)+15]))
#define ANCHOR64(a) do { ANCHOR16(a, 0); ANCHOR16(a, 16); \
                         ANCHOR16(a, 32); ANCHOR16(a, 48); } while (0)

// ---------------------------------------------------------------------------
// R17 = R15 verbatim (verified best: seq 893us, total 1007us, absmax 0.0).
// R16's permlane16 hybrid regressed (1032us): the v1 bpermute latency was
// already covered; permlane added serial head-of-chain work. Search ledger:
// broadcast mechanism (7 variants: fused-DPP best), EP cadence (16 optimum),
// DPP guards (minimized), chain packing (2x worse), MFMA (slower), f16/fdot2
// (slower), clock (falsified). This kernel is the measured optimum.
// ---------------------------------------------------------------------------
#define ROTF(acc, v, w, R) \
    asm("v_fmac_f32_dpp %0, %1, %2 row_ror:" #R " row_mask:0xf bank_mask:0xf" \
        : "+v"(acc) : "v"(v), "v"(w))

// Hazard-guarded copy: dst is safe as a DPP source for anything sequenced
// after this blob (s_nop 1 = 2 wait states).
#define MOVNOP(dst, src) \
    asm("v_mov_b32 %0, %1\n\ts_nop 1" : "=v"(dst) : "v"(src))

// One 16-rotation block: r=0 plain fma, r=1..15 fused DPP. acc index = r & 3.
#define KBLOCK(v, wd, B) do { \
    a0 = fmaf((v), (wd)[(B) + 0], a0); \
    ROTF(a1, (v), (wd)[(B) + 1],  1);  ROTF(a2, (v), (wd)[(B) + 2],  2); \
    ROTF(a3, (v), (wd)[(B) + 3],  3);  ROTF(a0, (v), (wd)[(B) + 4],  4); \
    ROTF(a1, (v), (wd)[(B) + 5],  5);  ROTF(a2, (v), (wd)[(B) + 6],  6); \
    ROTF(a3, (v), (wd)[(B) + 7],  7);  ROTF(a0, (v), (wd)[(B) + 8],  8); \
    ROTF(a1, (v), (wd)[(B) + 9],  9);  ROTF(a2, (v), (wd)[(B) +10], 10); \
    ROTF(a3, (v), (wd)[(B) +11], 11);  ROTF(a0, (v), (wd)[(B) +12], 12); \
    ROTF(a1, (v), (wd)[(B) +13], 13);  ROTF(a2, (v), (wd)[(B) +14], 14); \
    ROTF(a3, (v), (wd)[(B) +15], 15); \
} while (0)

// One recurrence step. bpermutes issue first (LDS pipe); latency hides under
// KBLOCK0. v1/v2/v3 are DS-returns: safe as DPP sources after the compiler's
// lgkmcnt wait (no VALU forwarding hazard) -> used directly.
__device__ __forceinline__ float rnn_step_dpp(const float (&wd)[64], float init, float hp,
                                              int a16, int a32, int a48) {
    const int hb = __float_as_int(hp);
    const int b1i = __builtin_amdgcn_ds_bpermute(a16, hb);   // h[i^16]
    const int b2i = __builtin_amdgcn_ds_bpermute(a32, hb);   // h[i^32]
    const int b3i = __builtin_amdgcn_ds_bpermute(a48, hb);   // h[i^48]
    float hpD; MOVNOP(hpD, hp);        // hp IS a VALU write -> keep guard
    float a0 = init, a1 = 0.f, a2 = 0.f, a3 = 0.f;
    KBLOCK(hpD, wd, 0);
    const float v1 = __int_as_float(b1i); KBLOCK(v1, wd, 16);
    const float v2 = __int_as_float(b2i); KBLOCK(v2, wd, 32);
    const float v3 = __int_as_float(b3i); KBLOCK(v3, wd, 48);
    return fast_tanh((a0 + a1) + (a2 + a3));
}

// Pre-permuted weight row for the DPP decomposition (verified R6/R7, absmax 0).
__device__ __forceinline__ void load_wdpp(const float* __restrict__ W, int lane,
                                          bool dirplus, float (&wd)[64]) {
#pragma unroll
    for (int m = 0; m < 64; ++m) {
        const int k = m >> 4, r = m & 15;
        const int lowoff = dirplus ? r : ((16 - r) & 15);
        const int j = ((lane & 48) | ((lane + lowoff) & 15)) ^ (k << 4);
        wd[m] = W[lane * 64 + j];
    }
}

// ---------------------------------------------------------------------------
// prep: pre[s][t][i] = b_ih0[i] + b_hh0[i] + sum_d W_ih0[i][d] * in[0,t,d]
// Only batch element 0 of x / y matters (reference uses e[0], o[0] only).
// ---------------------------------------------------------------------------
__global__ void prep_kernel(const float* __restrict__ x, const float* __restrict__ y,
                            const float* __restrict__ eW, const float* __restrict__ ebi,
                            const float* __restrict__ ebh,
                            const float* __restrict__ oW, const float* __restrict__ obi,
                            const float* __restrict__ obh,
                            float* __restrict__ pre)
{
    int idx = blockIdx.x * blockDim.x + threadIdx.x;   // 2*T*64 threads
    int i = idx & 63;
    int t = (idx >> 6) & (T - 1);
    int s = idx >> 18;
    const float* in = s ? y : x;          // batch 0 = first T*3 floats
    const float* W  = s ? oW : eW;        // [64][3]
    const float* bi = s ? obi : ebi;
    const float* bh = s ? obh : ebh;
    float v = bi[i] + bh[i]
            + W[i*3+0]*in[t*3+0] + W[i*3+1]*in[t*3+1] + W[i*3+2]*in[t*3+2];
    pre[idx] = v;
}

// ---------------------------------------------------------------------------
// seq: grid=2 (one block per RNN), 4 specialized waves, barrier per EP epoch.
//   wave0 @ epoch k: h0[t] = tanh(p[t] + Whh0@h0[t-1]), t in [16k, 16k+16)
//   wave1/wave2 @ epoch k: q[t] = b1 + Wih1@h0[t], t-split halves of [16k-16,16k)
//   wave3 @ epoch k: h1[t] = tanh(q[t] + Whh1@h1[t-1]), t in [16k-32, 16k-16)
// Ring safety at EP=16 (mod-32 ring): wave0 writes {16k..16k+15}, helpers
// read {16k-16..16k-1} (disjoint halves); helpers write qring {16k-16..16k-1},
// wave3 reads {16k..16k+15} mod 32 (disjoint). Readers >=1 barrier behind.
// ---------------------------------------------------------------------------
__global__ __launch_bounds__(256, 1) void seq_kernel(
    const float* __restrict__ pre,            // [2][T][64]
    const float* __restrict__ eWhh0, const float* __restrict__ eWih1,
    const float* __restrict__ eWhh1, const float* __restrict__ ebih1,
    const float* __restrict__ ebhh1,
    const float* __restrict__ oWhh0, const float* __restrict__ oWih1,
    const float* __restrict__ oWhh1, const float* __restrict__ obih1,
    const float* __restrict__ obhh1,
    float* __restrict__ hlast)                // [2][64]
{
    const int s    = blockIdx.x;
    const int wv   = threadIdx.x >> 6;
    const int lane = threadIdx.x & 63;

    __shared__ __align__(16) float h0ring[RING][64];
    __shared__ __align__(16) float qring[RING][64];

    const float* p = pre + s * T * 64;

    // Probe the hardware row_ror direction (wave-uniform result; R6-verified).
    const int got = __builtin_amdgcn_update_dpp(0, lane, 0x121, 0xF, 0xF, false);
    const bool dirplus = ((got & 15) == ((lane + 1) & 15));
    // bpermute byte-addresses for the three XOR-copies
    const int a16 = (lane ^ 16) << 2;
    const int a32 = (lane ^ 32) << 2;
    const int a48 = (lane ^ 48) << 2;

    if (wv == 0) {
        // ---------- layer-0 recurrence wave ----------
        const float* Whh0 = s ? oWhh0 : eWhh0;
        float wd[64];
        load_wdpp(Whh0, lane, dirplus, wd);

        float hp = 0.f;                        // h0[t-1]
        float pc[EP], pn[EP];
#pragma unroll
        for (int i = 0; i < EP; ++i) pc[i] = p[i * 64 + lane];

        for (int k = 0; k < NEP; ++k) {
            ANCHOR64(wd);                      // keep weight row resident
            const int base = k * EP;
            // prefetch next epoch's p (consumed next epoch -> latency hidden)
#pragma unroll
            for (int i = 0; i < EP; ++i) {
                int t = base + EP + i;
                pn[i] = (t < T) ? p[t * 64 + lane] : 0.f;
            }
            if (base < T) {                    // wave-uniform scalar branch
#pragma unroll
                for (int i = 0; i < EP; ++i) {
                    hp = rnn_step_dpp(wd, pc[i], hp, a16, a32, a48);
                    h0ring[(base + i) & (RING - 1)][lane] = hp;   // publish
                }
            }
#pragma unroll
            for (int i = 0; i < EP; ++i) pc[i] = pn[i];
            __syncthreads();
        }
    } else if (wv <= 2) {
        // ---------- helper waves: layer-1 input projection, t-split ----------
        const float* Wih1 = s ? oWih1 : eWih1;
        const float  b1   = s ? (obih1[lane] + obhh1[lane])
                              : (ebih1[lane] + ebhh1[lane]);
        float wi[64];
#pragma unroll
        for (int j = 0; j < 64; ++j) wi[j] = Wih1[lane * 64 + j];

        const int i0 = (wv - 1) * (EP / 2);    // wave1: t 0..7, wave2: t 8..15

        for (int k = 0; k < NEP; ++k) {
            ANCHOR64(wi);
            const int base = k * EP - EP;
            if (base >= 0 && base < T) {
#pragma unroll
                for (int i = 0; i < EP / 2; ++i) {
                    const int t = base + i0 + i;
                    const float4* hv = (const float4*)h0ring[t & (RING - 1)];
                    float q[4] = { b1, 0.f, 0.f, 0.f };
#pragma unroll
                    for (int j4 = 0; j4 < 16; ++j4) {
                        float4 u = hv[j4];
                        q[0] = fmaf(wi[4*j4+0], u.x, q[0]);
                        q[1] = fmaf(wi[4*j4+1], u.y, q[1]);
                        q[2] = fmaf(wi[4*j4+2], u.z, q[2]);
                        q[3] = fmaf(wi[4*j4+3], u.w, q[3]);
                    }
                    qring[t & (RING - 1)][lane] = (q[0] + q[1]) + (q[2] + q[3]);
                }
            }
            __syncthreads();
        }
    } else {
        // ---------- layer-1 recurrence wave ----------
        const float* Whh1 = s ? oWhh1 : eWhh1;
        float wd[64];
        load_wdpp(Whh1, lane, dirplus, wd);

        float hp = 0.f;                        // h1[t-1]
        for (int k = 0; k < NEP; ++k) {
            ANCHOR64(wd);
            const int base = k * EP - 2 * EP;
            if (base >= 0) {                   // base+EP-1 <= T-1 by construction
                float qb[EP];
#pragma unroll
                for (int i = 0; i < EP; ++i)   // all written >=1 epoch ago
                    qb[i] = qring[(base + i) & (RING - 1)][lane];
#pragma unroll
                for (int i = 0; i < EP; ++i)
                    hp = rnn_step_dpp(wd, qb[i], hp, a16, a32, a48);
            }
            __syncthreads();
        }
        hlast[s * 64 + lane] = hp;             // h1[T-1]
    }
}

// ---------------------------------------------------------------------------
// head: e0 = fce_w@hx + fce_b ; o0 = fco_w@hy + fco_b ; zz=[e0,o0,z];
//       h = relu(fc1_w@zz + fc1_b) ; out = fc2_w@h + fc2_b
// ---------------------------------------------------------------------------
__global__ void head_kernel(const float* __restrict__ hlast,   // [2][64]
                            const float* __restrict__ z,
                            const float* __restrict__ fce_w, const float* __restrict__ fce_b,
                            const float* __restrict__ fco_w, const float* __restrict__ fco_b,
                            const float* __restrict__ fc1_w, const float* __restrict__ fc1_b,
                            const float* __restrict__ fc2_w, const float* __restrict__ fc2_b,
                            float* __restrict__ out)            // [5]
{
    const int lane = threadIdx.x;   // 64 threads
    __shared__ float zz[9];
    __shared__ float hh[64];

    if (lane < 2) {
        float sacc = fce_b[lane];
        for (int j = 0; j < 64; ++j) sacc += fce_w[lane * 64 + j] * hlast[j];
        zz[lane] = sacc;
    } else if (lane < 4) {
        int r = lane - 2;
        float sacc = fco_b[r];
        for (int j = 0; j < 64; ++j) sacc += fco_w[r * 64 + j] * hlast[64 + j];
        zz[lane] = sacc;
    } else if (lane < 9) {
        zz[lane] = z[lane - 4];
    }
    __syncthreads();

    float sacc = fc1_b[lane];
#pragma unroll
    for (int j = 0; j < 9; ++j) sacc += fc1_w[lane * 9 + j] * zz[j];
    hh[lane] = fmaxf(sacc, 0.f);
    __syncthreads();

    if (lane < 5) {
        float o = fc2_b[lane];
        for (int i = 0; i < 64; ++i) o += fc2_w[lane * 64 + i] * hh[i];
        out[lane] = o;
    }
}

// ---------------------------------------------------------------------------
extern "C" void kernel_launch(void* const* d_in, const int* in_sizes, int n_in,
                              void* d_out, int out_size, void* d_ws, size_t ws_size,
                              hipStream_t stream)
{
    const float* x      = (const float*)d_in[0];
    const float* y      = (const float*)d_in[1];
    const float* z      = (const float*)d_in[2];
    const float* e_Wih0 = (const float*)d_in[3];
    const float* e_Whh0 = (const float*)d_in[4];
    const float* e_bih0 = (const float*)d_in[5];
    const float* e_bhh0 = (const float*)d_in[6];
    const float* e_Wih1 = (const float*)d_in[7];
    const float* e_Whh1 = (const float*)d_in[8];
    const float* e_bih1 = (const float*)d_in[9];
    const float* e_bhh1 = (const float*)d_in[10];
    const float* o_Wih0 = (const float*)d_in[11];
    const float* o_Whh0 = (const float*)d_in[12];
    const float* o_bih0 = (const float*)d_in[13];
    const float* o_bhh0 = (const float*)d_in[14];
    const float* o_Wih1 = (const float*)d_in[15];
    const float* o_Whh1 = (const float*)d_in[16];
    const float* o_bih1 = (const float*)d_in[17];
    const float* o_bhh1 = (const float*)d_in[18];
    const float* fce_w  = (const float*)d_in[19];
    const float* fce_b  = (const float*)d_in[20];
    const float* fco_w  = (const float*)d_in[21];
    const float* fco_b  = (const float*)d_in[22];
    const float* fc1_w  = (const float*)d_in[23];
    const float* fc1_b  = (const float*)d_in[24];
    const float* fc2_w  = (const float*)d_in[25];
    const float* fc2_b  = (const float*)d_in[26];

    float* pre   = (float*)d_ws;            // 2*T*64 floats = 2 MB
    float* hlast = pre + 2 * T * 64;        // 128 floats
    float* out   = (float*)d_out;

    prep_kernel<<<(2 * T * 64) / 256, 256, 0, stream>>>(
        x, y, e_Wih0, e_bih0, e_bhh0, o_Wih0, o_bih0, o_bhh0, pre);

    seq_kernel<<<2, 256, 0, stream>>>(
        pre,
        e_Whh0, e_Wih1, e_Whh1, e_bih1, e_bhh1,
        o_Whh0, o_Wih1, o_Whh1, o_bih1, o_bhh1,
        hlast);

    head_kernel<<<1, 64, 0, stream>>>(
        hlast, z, fce_w, fce_b, fco_w, fco_b, fc1_w, fc1_b, fc2_w, fc2_b, out);
}